// Round 1
// 1493.438 us; speedup vs baseline: 1.1806x; 1.1806x over previous
//
#include <hip/hip_runtime.h>
#include <math.h>

#define WSZ 8
#define SSZ 4
#define NHD 6
#define CHD 16
#define CCH 96
#define NPT 64
#define HH  256
#define WWI 256
#define QSCALE 0.25f
#define NEGV (-1e9f)
#define EPSV 1e-5f
#define XP 97            // odd row stride for LDS matrices -> conflict-free per-lane access

// ---------------------------------------------------------------------------
// Fully fused shifted-window blind-spot block:
//   attn (flash online softmax) + residual + LN1 + proj + LN2 + MLP + residual
// One block per window (8192), 384 threads = 6 waves = 6 heads, lane = token.
// LDS: single 12416-float buffer, phase-reused:  K|V  ->  X_hat  ->  P_hat|H
//   53504 B total -> 3 blocks/CU (vs 75776 B / 1 block before).
// Flash softmax keeps live registers ~90 (no s[64] blob) so regs don't cap
// the 18-wave/CU occupancy target.
// ---------------------------------------------------------------------------
__global__ __launch_bounds__(384, 4)
void fused_block_kernel(const float* __restrict__ q_g, const float* __restrict__ k_g,
                        const float* __restrict__ v_g, const float* __restrict__ rpb,
                        const float* __restrict__ ng,  const float* __restrict__ nb,
                        const float* __restrict__ pw,  const float* __restrict__ pb,
                        const float* __restrict__ g2,  const float* __restrict__ b2,
                        const float* __restrict__ w1,  const float* __restrict__ bb1,
                        const float* __restrict__ w2,  const float* __restrict__ bb2,
                        float* __restrict__ out)
{
    __shared__ __align__(16) float sB[2 * NPT * XP];   // 12416 floats = 49664 B
    __shared__ float sPS[NHD * NPT];                   // LN partial sums
    __shared__ float sPQ[NHD * NPT];                   // LN partial sumsq
    __shared__ float sMu[NPT], sRs[NPT];
    __shared__ int   sRid[NPT];

    const int n  = blockIdx.x;
    const int b  = n >> 10;
    const int nw = n & 1023;
    const int wh = nw >> 5, ww = nw & 31;
    const int t  = threadIdx.x;
    const int head = __builtin_amdgcn_readfirstlane(t >> 6);  // wave-uniform
    const int p  = t & 63;

    const long long img_base = (long long)b * (HH * WWI * CCH);

    float* sK = sB;                 // [64][96] during attention
    float* sV = sB + NPT * CCH;     // [64][96] during attention

    // ---- stage K,V: linear LDS layout (conflict-free b128 writes) ----------
    #pragma unroll
    for (int i = 0; i < 4; ++i) {
        int idx4 = t + i * 384;             // [0,1536)
        int pp   = idx4 / 24;               // token
        int cc   = (idx4 % 24) * 4;         // channel
        int rr = pp >> 3, c2 = pp & 7;
        int gh = (wh * 8 + rr + SSZ) & 255;
        int gw = (ww * 8 + c2 + SSZ) & 255;
        long long ga = img_base + (long long)(gh * WWI + gw) * CCH + cc;
        *(float4*)(&sK[idx4 * 4]) = *(const float4*)(k_g + ga);
        *(float4*)(&sV[idx4 * 4]) = *(const float4*)(v_g + ga);
    }
    // ---- region ids (shifted-grid coords, per Swin mask construction) ------
    if (t < 64) {
        int rr = t >> 3, c2 = t & 7;
        int hh2 = wh * 8 + rr;
        int ww2 = ww * 8 + c2;
        int rh = (hh2 < HH - WSZ) ? 0 : ((hh2 < HH - SSZ) ? 1 : 2);
        int rw = (ww2 < WWI - WSZ) ? 0 : ((ww2 < WWI - SSZ) ? 1 : 2);
        sRid[t] = rh * 3 + rw;
    }

    // ---- own q row (scaled), kept in regs ----------------------------------
    const int r1 = p >> 3, c1 = p & 7;
    const int gh1 = (wh * 8 + r1 + SSZ) & 255;
    const int gw1 = (ww * 8 + c1 + SSZ) & 255;
    float q[16];
    {
        long long ga = img_base + (long long)(gh1 * WWI + gw1) * CCH + head * CHD;
        #pragma unroll
        for (int i = 0; i < 16; i += 4) {
            float4 v4 = *(const float4*)(q_g + ga + i);
            q[i+0] = v4.x * QSCALE; q[i+1] = v4.y * QSCALE;
            q[i+2] = v4.z * QSCALE; q[i+3] = v4.w * QSCALE;
        }
    }
    __syncthreads();                                       // (1) K,V,rid ready

    // ---- flash attention: 4 chunks of 16 keys ------------------------------
    const int rid_i = sRid[p];
    const float* biasbase = rpb + ((r1 + 7) * 15 + (c1 + 7)) * NHD + head;

    float acc[16];
    #pragma unroll
    for (int i = 0; i < 16; ++i) acc[i] = 0.f;
    float mrun = -1e30f, lrun = 0.f;

    for (int j0 = 0; j0 < 64; j0 += 16) {
        float sc[16];
        #pragma unroll
        for (int jj = 0; jj < 16; ++jj) {
            const int j = j0 + jj;
            const float* kr = &sK[j * CCH + head * CHD];   // broadcast reads
            float4 k0 = *(const float4*)(kr +  0);
            float4 k1 = *(const float4*)(kr +  4);
            float4 k2 = *(const float4*)(kr +  8);
            float4 k3 = *(const float4*)(kr + 12);
            float d0 = q[0]*k0.x + q[1]*k0.y + q[2]*k0.z + q[3]*k0.w;
            float d1 = q[4]*k1.x + q[5]*k1.y + q[6]*k1.z + q[7]*k1.w;
            float d2 = q[8]*k2.x + q[9]*k2.y + q[10]*k2.z + q[11]*k2.w;
            float d3 = q[12]*k3.x + q[13]*k3.y + q[14]*k3.z + q[15]*k3.w;
            const int r2 = j >> 3, cc2 = j & 7;
            float bias = biasbase[-(r2 * 15 + cc2) * NHD];
            float msk = (sRid[j] != rid_i || j == p) ? NEGV : 0.0f;
            sc[jj] = (d0 + d1) + (d2 + d3) + bias + msk;
        }
        // chunk max (tree) + online rescale
        float m01 = fmaxf(sc[0],  sc[1]),  m23 = fmaxf(sc[2],  sc[3]);
        float m45 = fmaxf(sc[4],  sc[5]),  m67 = fmaxf(sc[6],  sc[7]);
        float m89 = fmaxf(sc[8],  sc[9]),  mab = fmaxf(sc[10], sc[11]);
        float mcd = fmaxf(sc[12], sc[13]), mef = fmaxf(sc[14], sc[15]);
        float mq = fmaxf(fmaxf(fmaxf(m01, m23), fmaxf(m45, m67)),
                         fmaxf(fmaxf(m89, mab), fmaxf(mcd, mef)));
        float mnew  = fmaxf(mrun, mq);
        float scale = __expf(mrun - mnew);                 // exp(-1e30-..)=0 first time
        lrun *= scale;
        #pragma unroll
        for (int i = 0; i < 16; ++i) acc[i] *= scale;
        #pragma unroll
        for (int jj = 0; jj < 16; ++jj) {
            const int j = j0 + jj;
            float pj = __expf(sc[jj] - mnew);
            lrun += pj;
            const float* vr = &sV[j * CCH + head * CHD];
            float4 v0 = *(const float4*)(vr +  0);
            float4 v1 = *(const float4*)(vr +  4);
            float4 v2 = *(const float4*)(vr +  8);
            float4 v3 = *(const float4*)(vr + 12);
            acc[0] += pj*v0.x;  acc[1] += pj*v0.y;  acc[2] += pj*v0.z;  acc[3] += pj*v0.w;
            acc[4] += pj*v1.x;  acc[5] += pj*v1.y;  acc[6] += pj*v1.z;  acc[7] += pj*v1.w;
            acc[8] += pj*v2.x;  acc[9] += pj*v2.y;  acc[10]+= pj*v2.z;  acc[11]+= pj*v2.w;
            acc[12]+= pj*v3.x;  acc[13]+= pj*v3.y;  acc[14]+= pj*v3.z;  acc[15]+= pj*v3.w;
        }
        mrun = mnew;
    }
    // normalize + residual (q already scaled): x lives in acc[]
    {
        float invl = 1.0f / lrun;
        #pragma unroll
        for (int i = 0; i < 16; ++i) acc[i] = acc[i] * invl + q[i];
    }
    // ---- LN1: register partials -> cross-wave reduce -----------------------
    {
        float s1 = 0.f, s2 = 0.f;
        #pragma unroll
        for (int i = 0; i < 16; ++i) { s1 += acc[i]; s2 += acc[i] * acc[i]; }
        sPS[head * 64 + p] = s1;
        sPQ[head * 64 + p] = s2;
    }
    __syncthreads();                                       // (2) K,V dead; partials ready
    if (t < 64) {
        float su = 0.f, sq = 0.f;
        #pragma unroll
        for (int h = 0; h < NHD; ++h) { su += sPS[h * 64 + t]; sq += sPQ[h * 64 + t]; }
        float mu  = su * (1.0f / 96.0f);
        float var = sq * (1.0f / 96.0f) - mu * mu;
        sMu[t] = mu;
        sRs[t] = 1.0f / sqrtf(var + EPSV);
    }
    __syncthreads();                                       // (3) stats ready
    // write LN1-normalized X_hat into sB[0..6207] (stride-97, conflict-free)
    {
        float mu = sMu[p], rs = sRs[p];
        #pragma unroll
        for (int i = 0; i < 16; ++i) {
            int ch = head * CHD + i;
            sB[p * XP + ch] = (acc[i] - mu) * rs * ng[ch] + nb[ch];
        }
    }
    __syncthreads();                                       // (4) X_hat ready

    // ---- proj: thread (head,p) -> output channels head*16..+15 of token p --
    float P[16];
    #pragma unroll
    for (int i = 0; i < 16; ++i) P[i] = pb[head * CHD + i];
    {
        const float* xrow = &sB[p * XP];
        const float* wb   = pw + head * CHD * CCH;         // wave-uniform -> s_load
        #pragma unroll 4
        for (int c = 0; c < CCH; ++c) {
            float xv = xrow[c];
            #pragma unroll
            for (int i = 0; i < 16; ++i) P[i] += xv * wb[i * CCH + c];
        }
    }
    // LN2 partials from P regs
    {
        float s1 = 0.f, s2 = 0.f;
        #pragma unroll
        for (int i = 0; i < 16; ++i) { s1 += P[i]; s2 += P[i] * P[i]; }
        sPS[head * 64 + p] = s1;
        sPQ[head * 64 + p] = s2;
    }
    __syncthreads();                                       // (5) X_hat dead; partials ready
    if (t < 64) {
        float su = 0.f, sq = 0.f;
        #pragma unroll
        for (int h = 0; h < NHD; ++h) { su += sPS[h * 64 + t]; sq += sPQ[h * 64 + t]; }
        float mu  = su * (1.0f / 96.0f);
        float var = sq * (1.0f / 96.0f) - mu * mu;
        sMu[t] = mu;
        sRs[t] = 1.0f / sqrtf(var + EPSV);
    }
    __syncthreads();                                       // (6) stats2 ready
    // write LN2-normalized P_hat into sB[0..6207]; raw P stays in regs (residual)
    {
        float mu = sMu[p], rs = sRs[p];
        #pragma unroll
        for (int i = 0; i < 16; ++i) {
            int ch = head * CHD + i;
            sB[p * XP + ch] = (P[i] - mu) * rs * g2[ch] + b2[ch];
        }
    }
    __syncthreads();                                       // (7) P_hat ready

    // ---- fc1 + exact GELU -> H region sB[6208..12415] ----------------------
    float hacc[16];
    #pragma unroll
    for (int i = 0; i < 16; ++i) hacc[i] = bb1[head * CHD + i];
    {
        const float* xrow = &sB[p * XP];
        const float* wb   = w1 + head * CHD * CCH;
        #pragma unroll 4
        for (int c = 0; c < CCH; ++c) {
            float xv = xrow[c];
            #pragma unroll
            for (int i = 0; i < 16; ++i) hacc[i] += xv * wb[i * CCH + c];
        }
    }
    {
        float* sH = sB + NPT * XP;
        #pragma unroll
        for (int i = 0; i < 16; ++i) {
            float h = hacc[i];
            h = 0.5f * h * (1.0f + erff(h * 0.70710678118654752f));
            sH[p * XP + head * CHD + i] = h;
        }
    }
    __syncthreads();                                       // (8) H ready

    // ---- fc2 + residual -> global ------------------------------------------
    #pragma unroll
    for (int i = 0; i < 16; ++i) hacc[i] = bb2[head * CHD + i];
    {
        const float* hrow = &sB[NPT * XP + p * XP];
        const float* wb   = w2 + head * CHD * CCH;
        #pragma unroll 4
        for (int c = 0; c < CCH; ++c) {
            float hv = hrow[c];
            #pragma unroll
            for (int i = 0; i < 16; ++i) hacc[i] += hv * wb[i * CCH + c];
        }
    }
    {
        float* op = out + img_base + (long long)(gh1 * WWI + gw1) * CCH + head * CHD;
        #pragma unroll
        for (int i = 0; i < 16; i += 4) {
            float4 v4;
            v4.x = P[i+0] + hacc[i+0];
            v4.y = P[i+1] + hacc[i+1];
            v4.z = P[i+2] + hacc[i+2];
            v4.w = P[i+3] + hacc[i+3];
            *(float4*)(op + i) = v4;
        }
    }
}

extern "C" void kernel_launch(void* const* d_in, const int* in_sizes, int n_in,
                              void* d_out, int out_size, void* d_ws, size_t ws_size,
                              hipStream_t stream) {
    (void)in_sizes; (void)n_in; (void)out_size; (void)d_ws; (void)ws_size;
    const float* q_g  = (const float*)d_in[0];
    const float* k_g  = (const float*)d_in[1];
    const float* v_g  = (const float*)d_in[2];
    const float* rpb  = (const float*)d_in[3];
    const float* ng   = (const float*)d_in[4];
    const float* nb   = (const float*)d_in[5];
    const float* pw   = (const float*)d_in[6];
    const float* pb   = (const float*)d_in[7];
    const float* g2   = (const float*)d_in[8];
    const float* b2   = (const float*)d_in[9];
    const float* w1   = (const float*)d_in[10];
    const float* bb1  = (const float*)d_in[11];
    const float* w2   = (const float*)d_in[12];
    const float* bb2  = (const float*)d_in[13];
    float* out = (float*)d_out;

    fused_block_kernel<<<dim3(8192), dim3(384), 0, stream>>>(
        q_g, k_g, v_g, rpb, ng, nb, pw, pb, g2, b2, w1, bb1, w2, bb2, out);
}